// Round 18
// baseline (158.632 us; speedup 1.0000x reference)
//
#include <hip/hip_runtime.h>
#include <math.h>

namespace {
constexpr int B   = 4;
constexpr int CIN = 128;   // high channels
constexpr int CO  = 64;    // up / aligned channels
constexpr int HF  = 64;    // high H=W
constexpr int HO  = 128;   // up/out H=W
constexpr int HW  = HO * HO;   // 16384
constexpr int NOFF = 27;   // 18 offset + 9 mask channels

// workspace layout (float units)
constexpr size_t UPB  = 0;                               // f16 [B][HO][HO][CO] up, NHWC
constexpr size_t LOB  = UPB + (size_t)B * HW * CO / 2;   // f16 [B][HO][HO][CO] low, NHWC
constexpr size_t HBF  = LOB + (size_t)B * HW * CO / 2;   // f16 [B][HF][HF][CIN] high, NHWC
constexpr size_t WFRG = HBF + (size_t)B * HF * HF * CIN / 2;   // k_dcn B-frags [4][18][64][8]
constexpr size_t WFUP = WFRG + (size_t)(4 * 18 * 64 * 8) / 2;  // k_up B-frags [9][4][4][64][8]
constexpr size_t WFOF = WFUP + (size_t)(9 * 4 * 4 * 64 * 8) / 2; // k_off B-frags [9][4][2][64][8]
}

using half8 = __attribute__((ext_vector_type(8))) _Float16;
using h2    = __attribute__((ext_vector_type(2))) _Float16;
using f32x4 = __attribute__((ext_vector_type(4))) float;

__device__ __forceinline__ unsigned short f2h16(float f) {
  return __builtin_bit_cast(unsigned short, (_Float16)f);
}
__device__ __forceinline__ unsigned pkh(float a, float b) {   // 2 f32 -> packed f16x2 (1 op)
  return __builtin_bit_cast(unsigned, __builtin_amdgcn_cvt_pkrtz(a, b));
}
__device__ __forceinline__ h2 u2h(unsigned u) { return __builtin_bit_cast(h2, u); }
__device__ __forceinline__ unsigned h2u(h2 v) { return __builtin_bit_cast(unsigned, v); }
__device__ __forceinline__ h2 dup_lo(unsigned u) {            // (lo,lo) via 1x v_perm_b32
  return u2h(__builtin_amdgcn_perm(u, u, 0x01000100u));
}
__device__ __forceinline__ h2 dup_hi(unsigned u) {            // (hi,hi)
  return u2h(__builtin_amdgcn_perm(u, u, 0x03020302u));
}

// ---------------- K0: weight repack (f16 frags) + high NCHW->f16 NHWC -------------
// blocks [0,288): repack; [288,1312): high cvt (one 32-ch chunk per block).
__global__ __launch_bounds__(256) void k_prep(const float* __restrict__ high,
                                              const float* __restrict__ wup,
                                              const float* __restrict__ woff,
                                              const float* __restrict__ wal,
                                              float* __restrict__ ws) {
  __shared__ unsigned short tl2[32][66];
  const int bid = blockIdx.x;
  const int t = threadIdx.x;

  if (bid < 288) {                           // ---- weight repack ----
    int i = bid * 256 + t;
    if (i < 4 * 18 * 64 * 8) {               // k_dcn: [w][kb][lane][j]
      int j = i & 7; int t2 = i >> 3;
      int lane = t2 & 63; int t3 = t2 >> 6;
      int kb = t3 % 18; int w = t3 / 18;
      int tap = kb >> 1;
      int c = (kb & 1) * 32 + ((lane >> 4) << 3) + j;
      int o = (w << 4) + (lane & 15);
      unsigned short* wfrag = (unsigned short*)(ws + WFRG);
      wfrag[i] = f2h16(wal[((size_t)o * CO + c) * 9 + tap]);
    }
    if (i < 9 * 4 * 4 * 64 * 8) {            // k_up: [rr][ch][w][lane][j]
      int j = i & 7; int lane = (i >> 3) & 63; int w = (i >> 9) & 3;
      int ch = (i >> 11) & 3; int rr = i >> 13;
      int c = ch * 32 + ((lane >> 4) << 3) + j;
      int o = w * 16 + (lane & 15);
      unsigned short* wfup = (unsigned short*)(ws + WFUP);
      wfup[i] = f2h16(wup[((size_t)c * CO + o) * 9 + rr]);
    }
    if (i < 9 * 4 * 2 * 64 * 8) {            // k_off: [tap][kc][nt][lane][j]
      int j = i & 7; int lane = (i >> 3) & 63; int nt = (i >> 9) & 1;
      int kc = (i >> 10) & 3; int tap = i >> 12;
      int c = kc * 32 + ((lane >> 4) << 3) + j;
      int o = nt * 16 + (lane & 15);
      float v = 0.f;
      if (o < NOFF) v = woff[(((size_t)o * 2 * CO + c) * 3 + tap / 3) * 3 + (tap % 3)];
      unsigned short* wfo = (unsigned short*)(ws + WFOF);
      wfo[i] = f2h16(v);
    }
    return;
  }

  {                                          // ---- high fp32 NCHW -> f16 NHWC ----
    unsigned short* hbf = (unsigned short*)(ws + HBF);
    int j = bid - 288;                       // [0,1024): (c-chunk, y, b)
    const int c0 = (j & 3) * 32;
    const int y = (j >> 2) & 63, b = j >> 8;
    const int x = t & 63, clb = t >> 6;
#pragma unroll
    for (int k = 0; k < 8; ++k) {
      int cl = clb * 8 + k;
      float v = high[(((size_t)b * CIN + c0 + cl) * HF + y) * HF + x];
      tl2[cl][x] = f2h16(v);
    }
    __syncthreads();
    int px = t >> 2, cg = t & 3;
    ushort4 a, bb;
    a.x = tl2[cg * 8 + 0][px]; a.y = tl2[cg * 8 + 1][px];
    a.z = tl2[cg * 8 + 2][px]; a.w = tl2[cg * 8 + 3][px];
    bb.x = tl2[cg * 8 + 4][px]; bb.y = tl2[cg * 8 + 5][px];
    bb.z = tl2[cg * 8 + 6][px]; bb.w = tl2[cg * 8 + 7][px];
    unsigned short* dst = hbf + (((size_t)b * HF + y) * HF + px) * CIN + c0 + cg * 8;
    *(ushort4*)(dst) = a;
    *(ushort4*)(dst + 4) = bb;
  }
}

// ---------------- K1: transposed conv MFMA GEMM + (independent) low-cvt blocks ----
// blocks [0,1024): up tiles (XCD-swizzled); [1024,1536): low->f16 NHWC + out copy.
union SmemUp {
  unsigned short At[2][4][85][8];       // [buf][cg][5*17 px][8ch] f16 (10880 B)
  float accs[4][16][65];                // epilogue transpose (16640 B)
  unsigned short tl[64][130];           // low-cvt transpose tile (16640 B)
};

__global__ __launch_bounds__(256) void k_up(const float* __restrict__ low,
                                            const float* __restrict__ bup,
                                            float* __restrict__ out,
                                            float* __restrict__ ws) {
  __shared__ SmemUp sm;
  const int t = threadIdx.x;

  if (blockIdx.x >= 1024) {            // ---- low fp32 NCHW -> f16 NHWC + out copy ----
    unsigned short* lob = (unsigned short*)(ws + LOB);
    int j = blockIdx.x - 1024;
    const int y = j & 127, b = j >> 7;
#pragma unroll
    for (int it = 0; it < 8; ++it) {   // 2048 float4 over 256 threads
      int i = it * 256 + t;
      int c = i >> 5, xi = (i & 31) * 4;
      float4 v = *(const float4*)(low + (((size_t)b * CO + c) * HO + y) * HO + xi);
      *(float4*)(out + (((size_t)b * 2 * CO + CO + c) * HO + y) * HO + xi) = v;
      sm.tl[c][xi + 0] = f2h16(v.x); sm.tl[c][xi + 1] = f2h16(v.y);
      sm.tl[c][xi + 2] = f2h16(v.z); sm.tl[c][xi + 3] = f2h16(v.w);
    }
    __syncthreads();
#pragma unroll
    for (int it = 0; it < 4; ++it) {   // 128 px x 8 cgroups
      int i = it * 256 + t;
      int x = i >> 3, cg = i & 7;
      unsigned rw[4];
#pragma unroll
      for (int p = 0; p < 4; ++p)
        rw[p] = (unsigned)sm.tl[cg * 8 + 2 * p][x] | ((unsigned)sm.tl[cg * 8 + 2 * p + 1][x] << 16);
      *(uint4*)(lob + (((size_t)b * HO + y) * HO + x) * CO + cg * 8) =
          make_uint4(rw[0], rw[1], rw[2], rw[3]);
    }
    return;
  }

  const unsigned short* hbf = (const unsigned short*)(ws + HBF);
  const uint4* wfu = (const uint4*)(ws + WFUP);
  unsigned short* upb = (unsigned short*)(ws + UPB);

  const int lane = t & 63;
  const int oq   = __builtin_amdgcn_readfirstlane(t >> 6);
  const int orig = blockIdx.x;
  const int tile = ((orig & 7) << 7) + (orig >> 3);   // XCD swizzle (1024 = 8*128)
  const int par  = tile & 3;
  const int pyv  = (par >> 1) & 1, pxv = par & 1;
  const int tx   = ((tile >> 2) & 3) * 16;
  const int ty   = ((tile >> 4) & 15) * 4;
  const int b    = tile >> 8;
  const int nty  = pyv + 1, ntx = pxv + 1;

  uint4 s0, s1;
  const int pxA = t >> 2, cgA = t & 3;
  const int i2 = t + 256, pxB = i2 >> 2, cgB = i2 & 3;

  auto load_chunk = [&](int c0) {
    {
      int gy = ty + pxA / 17, gx = tx + pxA % 17;
      s0 = make_uint4(0, 0, 0, 0);
      if (gy < HF && gx < HF)
        s0 = *(const uint4*)(hbf + (((size_t)b * HF + gy) * HF + gx) * CIN + c0 + cgA * 8);
    }
    s1 = make_uint4(0, 0, 0, 0);
    if (pxB < 85) {
      int gy = ty + pxB / 17, gx = tx + pxB % 17;
      if (gy < HF && gx < HF)
        s1 = *(const uint4*)(hbf + (((size_t)b * HF + gy) * HF + gx) * CIN + c0 + cgB * 8);
    }
  };
  auto write_chunk = [&](int buf) {
    *(uint4*)&sm.At[buf][cgA][pxA][0] = s0;
    if (pxB < 85) *(uint4*)&sm.At[buf][cgB][pxB][0] = s1;
  };

  f32x4 acc[4];
#pragma unroll
  for (int mt = 0; mt < 4; ++mt) acc[mt] = {0.f, 0.f, 0.f, 0.f};

  load_chunk(0);
  write_chunk(0);
  __syncthreads();

  union Cvt { uint4 u; half8 h; };
  int buf = 0;
#pragma unroll 1
  for (int ch = 0; ch < 4; ++ch) {
    if (ch < 3) load_chunk((ch + 1) * 32);
#pragma unroll
    for (int ti = 0; ti < 2; ++ti) {
      if (ti < nty) {
#pragma unroll
        for (int tj = 0; tj < 2; ++tj) {
          if (tj < ntx) {
            int ryA = pyv ? 2 - 2 * ti : 1;
            int rxA = pxv ? 2 - 2 * tj : 1;
            int rr = ryA * 3 + rxA;
            Cvt bw; bw.u = wfu[(((size_t)rr * 4 + ch) * 4 + oq) * 64 + lane];
#pragma unroll
            for (int mt = 0; mt < 4; ++mt) {
              Cvt av;
              av.u = *(const uint4*)&sm.At[buf][lane >> 4][(mt + ti) * 17 + (lane & 15) + tj][0];
              acc[mt] = __builtin_amdgcn_mfma_f32_16x16x32_f16(av.h, bw.h, acc[mt], 0, 0, 0);
            }
          }
        }
      }
    }
    if (ch < 3) write_chunk(buf ^ 1);
    __syncthreads();
    buf ^= 1;
  }

  // epilogue: transpose via padded LDS, f16 NHWC stores + bias
#pragma unroll
  for (int mt = 0; mt < 4; ++mt)
#pragma unroll
    for (int r = 0; r < 4; ++r)
      sm.accs[oq][lane & 15][mt * 16 + (lane >> 4) * 4 + r] = acc[mt][r];
  __syncthreads();

  const int yo = 2 * (ty + (lane >> 4)) + pyv;
  const int xo = 2 * (tx + (lane & 15)) + pxv;
  unsigned short* dst = upb + (((size_t)b * HO + yo) * HO + xo) * CO + oq * 16;
  unsigned rw[8];
#pragma unroll
  for (int p = 0; p < 8; ++p) {
    float v0 = sm.accs[oq][2 * p][lane] + bup[oq * 16 + 2 * p];
    float v1 = sm.accs[oq][2 * p + 1][lane] + bup[oq * 16 + 2 * p + 1];
    rw[p] = pkh(v0, v1);
  }
  *(uint4*)dst = make_uint4(rw[0], rw[1], rw[2], rw[3]);
  *(uint4*)(dst + 8) = make_uint4(rw[4], rw[5], rw[6], rw[7]);
}

// ---------------- K2: FUSED offset-conv (MFMA) + modulated deformable conv --------
// Tile 64 px (16x4), 1D grid 1024 XCD-swizzled. fo never leaves LDS.
// Phase 3 rewritten LDS-FREE: each lane gathers + bilinear-combines its OWN MFMA
// A-fragment in-register (px = mt*16+(lane&15), ch-group = kb2*4+(lane>>4)).
// Zero barriers / zero LDS in phase 3; 4 waves redundantly cover the tile
// (L1/L2-absorbed). prm is read-only broadcast after phase 2.
// LDS arena 27648 B -> 5 blocks/CU:
//   phase1: in[16][108][8] f16 @0 (27648 B)
//   phase2: fo_raw[32][66] f32 @0 (8448) + prm u32 [9][64][3] @8448 (6912)
//   phase4: accs[4][16][65] f32 @0 (16640)
__global__ __launch_bounds__(256) void k_offdcn(const float* __restrict__ boff,
                                                const float* __restrict__ bal,
                                                float* __restrict__ out,
                                                const float* __restrict__ ws) {
  __shared__ float smem[6912];          // 27648 B
  unsigned short* us_in = (unsigned short*)smem;
  float* fo_raw = smem;                                    // [32][66]
  unsigned* prm = (unsigned*)(smem + 2112);                // [9][64][3]

  const unsigned short* upb = (const unsigned short*)(ws + UPB);
  const unsigned short* lob = (const unsigned short*)(ws + LOB);
  const uint4* wfo = (const uint4*)(ws + WFOF);
  const uint4* wf  = (const uint4*)(ws + WFRG);

  const int t = threadIdx.x;
  const int lane = t & 63;
  const int w = __builtin_amdgcn_readfirstlane(t >> 6);
  const int mh = w >> 1, nt = w & 1;    // phase-1 roles
  const int oq = w;                     // phase-3 role
  const int orig = blockIdx.x;
  const int tile = ((orig & 7) << 7) + (orig >> 3);   // XCD swizzle (1024 = 8*128)
  const int tX = (tile & 7) * 16;
  const int tY = ((tile >> 3) & 31) * 4;
  const int b  = tile >> 8;
  const unsigned short* upB = upb + (size_t)b * HW * CO;

  union Cvt { uint4 u; half8 h; };

  // ================= phase 1: 3x3 conv over concat(up,low) -> fo_raw ==============
  for (int i = t; i < 16 * 108; i += 256) {
    int px = i >> 4, cg = i & 15;
    int gy = tY - 1 + px / 18, gx = tX - 1 + px % 18;
    uint4 v = make_uint4(0, 0, 0, 0);
    if (gy >= 0 && gy < HO && gx >= 0 && gx < HO) {
      const unsigned short* src =
          (cg < 8 ? upb : lob) + (((size_t)b * HO + gy) * HO + gx) * CO + (cg & 7) * 8;
      v = *(const uint4*)src;
    }
    *(uint4*)&us_in[((size_t)cg * 108 + px) * 8] = v;
  }
  __syncthreads();

  f32x4 acc2[2];
  acc2[0] = {0.f, 0.f, 0.f, 0.f}; acc2[1] = {0.f, 0.f, 0.f, 0.f};
#pragma unroll 1
  for (int tap = 0; tap < 9; ++tap) {
    int ky = tap / 3, kx = tap % 3;
#pragma unroll
    for (int kc = 0; kc < 4; ++kc) {
      Cvt bw; bw.u = wfo[(((size_t)tap * 4 + kc) * 2 + nt) * 64 + lane];
#pragma unroll
      for (int mt = 0; mt < 2; ++mt) {
        int sy = mh * 2 + mt;
        Cvt av;
        av.u = *(const uint4*)&us_in[(((size_t)(kc * 4 + (lane >> 4))) * 108 +
                                      (sy + ky) * 18 + (lane & 15) + kx) * 8];
        acc2[mt] = __builtin_amdgcn_mfma_f32_16x16x32_f16(av.h, bw.h, acc2[mt], 0, 0, 0);
      }
    }
  }
  __syncthreads();

#pragma unroll
  for (int mt = 0; mt < 2; ++mt)
#pragma unroll
    for (int r = 0; r < 4; ++r)
      fo_raw[(nt * 16 + (lane & 15)) * 66 + mh * 32 + mt * 16 + (lane >> 4) * 4 + r] =
          acc2[mt][r];
  __syncthreads();

  // ================= phase 2: bilinear params from LDS fo ==========================
  for (int i = t; i < 9 * 64; i += 256) {
    int k = i >> 6, px = i & 63;
    int y = tY + (px >> 4), x = tX + (px & 15);
    float offy = fo_raw[(2 * k) * 66 + px] + boff[2 * k];
    float offx = fo_raw[(2 * k + 1) * 66 + px] + boff[2 * k + 1];
    float m = 2.f / (1.f + expf(-(fo_raw[(18 + k) * 66 + px] + boff[18 + k])));
    float pyf = offy + (float)(y - 1 + k / 3);
    float pxf = offx + (float)(x - 1 + k % 3);
    float y0f = floorf(pyf), x0f = floorf(pxf);
    float wy = pyf - y0f, wx = pxf - x0f;
    int y0 = (int)y0f, x0 = (int)x0f;
    int y1 = y0 + 1, x1 = x0 + 1;
    float vy0 = (y0 >= 0 && y0 < HO) ? m : 0.f;
    float vy1 = (y1 >= 0 && y1 < HO) ? m : 0.f;
    float vx0 = (x0 >= 0 && x0 < HO) ? 1.f : 0.f;
    float vx1 = (x1 >= 0 && x1 < HO) ? 1.f : 0.f;
    float w0 = (1.f - wy) * (1.f - wx) * vy0 * vx0;
    float w1 = (1.f - wy) * wx * vy0 * vx1;
    float w2 = wy * (1.f - wx) * vy1 * vx0;
    float w3 = wy * wx * vy1 * vx1;
    int cy0 = min(max(y0, 0), HO - 1), cy1 = min(max(y1, 0), HO - 1);
    int cx0 = min(max(x0, 0), HO - 1), cx1 = min(max(x1, 0), HO - 1);
    unsigned pc = (unsigned)cy0 | ((unsigned)cy1 << 8) |
                  ((unsigned)cx0 << 16) | ((unsigned)cx1 << 24);
    unsigned* pr = prm + ((size_t)k * 64 + px) * 3;
    pr[0] = pkh(w0, w1);
    pr[1] = pkh(w2, w3);
    pr[2] = pc;
  }
  __syncthreads();

  // ================= phase 3: LDS-free per-lane gather + bilinear + MFMA ==========
  f32x4 acc[4];
#pragma unroll
  for (int mt = 0; mt < 4; ++mt) acc[mt] = {0.f, 0.f, 0.f, 0.f};

  const int qo = (lane >> 4) * 8;       // this lane's channel-group base (within 32)

#pragma unroll 1
  for (int tap = 0; tap < 9; ++tap) {
    uint4 bq0 = wf[(oq * 18 + 2 * tap) * 64 + lane];
    uint4 bq1 = wf[(oq * 18 + 2 * tap + 1) * 64 + lane];
#pragma unroll
    for (int mt = 0; mt < 4; ++mt) {
      const int px = mt * 16 + (lane & 15);
      const unsigned* pr = prm + ((size_t)tap * 64 + px) * 3;
      unsigned pw01 = pr[0], pw23 = pr[1], pc = pr[2];
      h2 w0 = dup_lo(pw01), w1 = dup_hi(pw01);
      h2 w2 = dup_lo(pw23), w3 = dup_hi(pw23);
      int cy0 = pc & 255, cy1 = (pc >> 8) & 255, cx0 = (pc >> 16) & 255, cx1 = pc >> 24;
      const unsigned short* p00 = upB + (size_t)(cy0 * HO + cx0) * CO;
      const unsigned short* p01 = upB + (size_t)(cy0 * HO + cx1) * CO;
      const unsigned short* p10 = upB + (size_t)(cy1 * HO + cx0) * CO;
      const unsigned short* p11 = upB + (size_t)(cy1 * HO + cx1) * CO;
#pragma unroll
      for (int kb2 = 0; kb2 < 2; ++kb2) {
        const int o8 = qo + kb2 * 32;
        uint4 v00 = *(const uint4*)(p00 + o8);
        uint4 v01 = *(const uint4*)(p01 + o8);
        uint4 v10 = *(const uint4*)(p10 + o8);
        uint4 v11 = *(const uint4*)(p11 + o8);
        unsigned q0[4] = {v00.x, v00.y, v00.z, v00.w};
        unsigned q1[4] = {v01.x, v01.y, v01.z, v01.w};
        unsigned q2[4] = {v10.x, v10.y, v10.z, v10.w};
        unsigned q3[4] = {v11.x, v11.y, v11.z, v11.w};
        unsigned rw[4];
#pragma unroll
        for (int p = 0; p < 4; ++p) {   // 4x v_pk_fma_f16 per pair of channels
          h2 r = w3 * u2h(q3[p]);
          r = __builtin_elementwise_fma(w2, u2h(q2[p]), r);
          r = __builtin_elementwise_fma(w1, u2h(q1[p]), r);
          r = __builtin_elementwise_fma(w0, u2h(q0[p]), r);
          rw[p] = h2u(r);
        }
        Cvt av; av.u = make_uint4(rw[0], rw[1], rw[2], rw[3]);
        Cvt bfr; bfr.u = kb2 ? bq1 : bq0;
        acc[mt] = __builtin_amdgcn_mfma_f32_16x16x32_f16(av.h, bfr.h, acc[mt], 0, 0, 0);
      }
    }
  }
  __syncthreads();                      // prm consumed; smem reused by epilogue

  // ================= phase 4: epilogue =============================================
  float* accs = smem;                    // [4][16][65]
#pragma unroll
  for (int mt = 0; mt < 4; ++mt)
#pragma unroll
    for (int r = 0; r < 4; ++r)
      accs[((size_t)oq * 16 + (lane & 15)) * 65 + mt * 16 + (lane >> 4) * 4 + r] = acc[mt][r];
  __syncthreads();

  const int y = tY + (lane >> 4), x = tX + (lane & 15);
  float* ob = out + (size_t)b * 2 * CO * HW + (size_t)y * HO + x;
#pragma unroll
  for (int ol = 0; ol < 16; ++ol) {
    int o = oq * 16 + ol;
    float v = accs[((size_t)oq * 16 + ol) * 65 + lane] + bal[o];
    v = (v >= 0.f) ? v : 0.2f * v;                // leaky relu
    ob[(size_t)o * HW] = v;
  }
}

extern "C" void kernel_launch(void* const* d_in, const int* in_sizes, int n_in,
                              void* d_out, int out_size, void* d_ws, size_t ws_size,
                              hipStream_t stream) {
  const float* high = (const float*)d_in[0];
  const float* low  = (const float*)d_in[1];
  const float* wup  = (const float*)d_in[2];
  const float* bup  = (const float*)d_in[3];
  const float* woff = (const float*)d_in[4];
  const float* boff = (const float*)d_in[5];
  const float* wal  = (const float*)d_in[6];
  const float* bal  = (const float*)d_in[7];
  float* out = (float*)d_out;
  float* ws  = (float*)d_ws;

  k_prep<<<dim3(1312), dim3(256), 0, stream>>>(high, wup, woff, wal, ws);
  k_up<<<dim3(1536), dim3(256), 0, stream>>>(low, bup, out, ws);
  k_offdcn<<<dim3(1024), dim3(256), 0, stream>>>(boff, bal, out, ws);
}

// Round 19
// 57.183 us; speedup vs baseline: 2.7741x; 2.7741x over previous
//
#include <hip/hip_runtime.h>
#include <math.h>

namespace {
constexpr int B   = 4;
constexpr int CIN = 128;   // high channels
constexpr int CO  = 64;    // up / aligned channels
constexpr int HF  = 64;    // high H=W
constexpr int HO  = 128;   // up/out H=W
constexpr int HW  = HO * HO;   // 16384
constexpr int NOFF = 27;   // 18 offset + 9 mask channels

// workspace layout (float units)
constexpr size_t UPB  = 0;                               // f16 [B][HO][HO][CO] up, NHWC
constexpr size_t LOB  = UPB + (size_t)B * HW * CO / 2;   // f16 [B][HO][HO][CO] low, NHWC
constexpr size_t HBF  = LOB + (size_t)B * HW * CO / 2;   // f16 [B][HF][HF][CIN] high, NHWC
constexpr size_t WFRG = HBF + (size_t)B * HF * HF * CIN / 2;   // k_dcn B-frags [4][18][64][8]
constexpr size_t WFUP = WFRG + (size_t)(4 * 18 * 64 * 8) / 2;  // k_up B-frags [9][4][4][64][8]
constexpr size_t WFOF = WFUP + (size_t)(9 * 4 * 4 * 64 * 8) / 2; // k_off B-frags [9][4][2][64][8]
}

using half8 = __attribute__((ext_vector_type(8))) _Float16;
using h2    = __attribute__((ext_vector_type(2))) _Float16;
using f32x4 = __attribute__((ext_vector_type(4))) float;

__device__ __forceinline__ unsigned short f2h16(float f) {
  return __builtin_bit_cast(unsigned short, (_Float16)f);
}
__device__ __forceinline__ unsigned pkh(float a, float b) {   // 2 f32 -> packed f16x2 (1 op)
  return __builtin_bit_cast(unsigned, __builtin_amdgcn_cvt_pkrtz(a, b));
}
__device__ __forceinline__ h2 u2h(unsigned u) { return __builtin_bit_cast(h2, u); }
__device__ __forceinline__ unsigned h2u(h2 v) { return __builtin_bit_cast(unsigned, v); }
__device__ __forceinline__ h2 dup_lo(unsigned u) {            // (lo,lo) via 1x v_perm_b32
  return u2h(__builtin_amdgcn_perm(u, u, 0x01000100u));
}
__device__ __forceinline__ h2 dup_hi(unsigned u) {            // (hi,hi)
  return u2h(__builtin_amdgcn_perm(u, u, 0x03020302u));
}

// ---------------- K0: weight repack (f16 frags) + high NCHW->f16 NHWC -------------
// blocks [0,288): repack; [288,1312): high cvt (one 32-ch chunk per block).
__global__ __launch_bounds__(256) void k_prep(const float* __restrict__ high,
                                              const float* __restrict__ wup,
                                              const float* __restrict__ woff,
                                              const float* __restrict__ wal,
                                              float* __restrict__ ws) {
  __shared__ unsigned short tl2[32][66];
  const int bid = blockIdx.x;
  const int t = threadIdx.x;

  if (bid < 288) {                           // ---- weight repack ----
    int i = bid * 256 + t;
    if (i < 4 * 18 * 64 * 8) {               // k_dcn: [w][kb][lane][j]
      int j = i & 7; int t2 = i >> 3;
      int lane = t2 & 63; int t3 = t2 >> 6;
      int kb = t3 % 18; int w = t3 / 18;
      int tap = kb >> 1;
      int c = (kb & 1) * 32 + ((lane >> 4) << 3) + j;
      int o = (w << 4) + (lane & 15);
      unsigned short* wfrag = (unsigned short*)(ws + WFRG);
      wfrag[i] = f2h16(wal[((size_t)o * CO + c) * 9 + tap]);
    }
    if (i < 9 * 4 * 4 * 64 * 8) {            // k_up: [rr][ch][w][lane][j]
      int j = i & 7; int lane = (i >> 3) & 63; int w = (i >> 9) & 3;
      int ch = (i >> 11) & 3; int rr = i >> 13;
      int c = ch * 32 + ((lane >> 4) << 3) + j;
      int o = w * 16 + (lane & 15);
      unsigned short* wfup = (unsigned short*)(ws + WFUP);
      wfup[i] = f2h16(wup[((size_t)c * CO + o) * 9 + rr]);
    }
    if (i < 9 * 4 * 2 * 64 * 8) {            // k_off: [tap][kc][nt][lane][j]
      int j = i & 7; int lane = (i >> 3) & 63; int nt = (i >> 9) & 1;
      int kc = (i >> 10) & 3; int tap = i >> 12;
      int c = kc * 32 + ((lane >> 4) << 3) + j;
      int o = nt * 16 + (lane & 15);
      float v = 0.f;
      if (o < NOFF) v = woff[(((size_t)o * 2 * CO + c) * 3 + tap / 3) * 3 + (tap % 3)];
      unsigned short* wfo = (unsigned short*)(ws + WFOF);
      wfo[i] = f2h16(v);
    }
    return;
  }

  {                                          // ---- high fp32 NCHW -> f16 NHWC ----
    unsigned short* hbf = (unsigned short*)(ws + HBF);
    int j = bid - 288;                       // [0,1024): (c-chunk, y, b)
    const int c0 = (j & 3) * 32;
    const int y = (j >> 2) & 63, b = j >> 8;
    const int x = t & 63, clb = t >> 6;
#pragma unroll
    for (int k = 0; k < 8; ++k) {
      int cl = clb * 8 + k;
      float v = high[(((size_t)b * CIN + c0 + cl) * HF + y) * HF + x];
      tl2[cl][x] = f2h16(v);
    }
    __syncthreads();
    int px = t >> 2, cg = t & 3;
    ushort4 a, bb;
    a.x = tl2[cg * 8 + 0][px]; a.y = tl2[cg * 8 + 1][px];
    a.z = tl2[cg * 8 + 2][px]; a.w = tl2[cg * 8 + 3][px];
    bb.x = tl2[cg * 8 + 4][px]; bb.y = tl2[cg * 8 + 5][px];
    bb.z = tl2[cg * 8 + 6][px]; bb.w = tl2[cg * 8 + 7][px];
    unsigned short* dst = hbf + (((size_t)b * HF + y) * HF + px) * CIN + c0 + cg * 8;
    *(ushort4*)(dst) = a;
    *(ushort4*)(dst + 4) = bb;
  }
}

// ---------------- K1: transposed conv MFMA GEMM + (independent) low-cvt blocks ----
// blocks [0,1024): up tiles (XCD-swizzled); [1024,1536): low->f16 NHWC + out copy.
union SmemUp {
  unsigned short At[2][4][85][8];       // [buf][cg][5*17 px][8ch] f16 (10880 B)
  float accs[4][16][65];                // epilogue transpose (16640 B)
  unsigned short tl[64][130];           // low-cvt transpose tile (16640 B)
};

__global__ __launch_bounds__(256) void k_up(const float* __restrict__ low,
                                            const float* __restrict__ bup,
                                            float* __restrict__ out,
                                            float* __restrict__ ws) {
  __shared__ SmemUp sm;
  const int t = threadIdx.x;

  if (blockIdx.x >= 1024) {            // ---- low fp32 NCHW -> f16 NHWC + out copy ----
    unsigned short* lob = (unsigned short*)(ws + LOB);
    int j = blockIdx.x - 1024;
    const int y = j & 127, b = j >> 7;
#pragma unroll
    for (int it = 0; it < 8; ++it) {   // 2048 float4 over 256 threads
      int i = it * 256 + t;
      int c = i >> 5, xi = (i & 31) * 4;
      float4 v = *(const float4*)(low + (((size_t)b * CO + c) * HO + y) * HO + xi);
      *(float4*)(out + (((size_t)b * 2 * CO + CO + c) * HO + y) * HO + xi) = v;
      sm.tl[c][xi + 0] = f2h16(v.x); sm.tl[c][xi + 1] = f2h16(v.y);
      sm.tl[c][xi + 2] = f2h16(v.z); sm.tl[c][xi + 3] = f2h16(v.w);
    }
    __syncthreads();
#pragma unroll
    for (int it = 0; it < 4; ++it) {   // 128 px x 8 cgroups
      int i = it * 256 + t;
      int x = i >> 3, cg = i & 7;
      unsigned rw[4];
#pragma unroll
      for (int p = 0; p < 4; ++p)
        rw[p] = (unsigned)sm.tl[cg * 8 + 2 * p][x] | ((unsigned)sm.tl[cg * 8 + 2 * p + 1][x] << 16);
      *(uint4*)(lob + (((size_t)b * HO + y) * HO + x) * CO + cg * 8) =
          make_uint4(rw[0], rw[1], rw[2], rw[3]);
    }
    return;
  }

  const unsigned short* hbf = (const unsigned short*)(ws + HBF);
  const uint4* wfu = (const uint4*)(ws + WFUP);
  unsigned short* upb = (unsigned short*)(ws + UPB);

  const int lane = t & 63;
  const int oq   = __builtin_amdgcn_readfirstlane(t >> 6);
  const int orig = blockIdx.x;
  const int tile = ((orig & 7) << 7) + (orig >> 3);   // XCD swizzle (1024 = 8*128)
  const int par  = tile & 3;
  const int pyv  = (par >> 1) & 1, pxv = par & 1;
  const int tx   = ((tile >> 2) & 3) * 16;
  const int ty   = ((tile >> 4) & 15) * 4;
  const int b    = tile >> 8;
  const int nty  = pyv + 1, ntx = pxv + 1;

  uint4 s0, s1;
  const int pxA = t >> 2, cgA = t & 3;
  const int i2 = t + 256, pxB = i2 >> 2, cgB = i2 & 3;

  auto load_chunk = [&](int c0) {
    {
      int gy = ty + pxA / 17, gx = tx + pxA % 17;
      s0 = make_uint4(0, 0, 0, 0);
      if (gy < HF && gx < HF)
        s0 = *(const uint4*)(hbf + (((size_t)b * HF + gy) * HF + gx) * CIN + c0 + cgA * 8);
    }
    s1 = make_uint4(0, 0, 0, 0);
    if (pxB < 85) {
      int gy = ty + pxB / 17, gx = tx + pxB % 17;
      if (gy < HF && gx < HF)
        s1 = *(const uint4*)(hbf + (((size_t)b * HF + gy) * HF + gx) * CIN + c0 + cgB * 8);
    }
  };
  auto write_chunk = [&](int buf) {
    *(uint4*)&sm.At[buf][cgA][pxA][0] = s0;
    if (pxB < 85) *(uint4*)&sm.At[buf][cgB][pxB][0] = s1;
  };

  f32x4 acc[4];
#pragma unroll
  for (int mt = 0; mt < 4; ++mt) acc[mt] = {0.f, 0.f, 0.f, 0.f};

  load_chunk(0);
  write_chunk(0);
  __syncthreads();

  union Cvt { uint4 u; half8 h; };
  int buf = 0;
#pragma unroll 1
  for (int ch = 0; ch < 4; ++ch) {
    if (ch < 3) load_chunk((ch + 1) * 32);
#pragma unroll
    for (int ti = 0; ti < 2; ++ti) {
      if (ti < nty) {
#pragma unroll
        for (int tj = 0; tj < 2; ++tj) {
          if (tj < ntx) {
            int ryA = pyv ? 2 - 2 * ti : 1;
            int rxA = pxv ? 2 - 2 * tj : 1;
            int rr = ryA * 3 + rxA;
            Cvt bw; bw.u = wfu[(((size_t)rr * 4 + ch) * 4 + oq) * 64 + lane];
#pragma unroll
            for (int mt = 0; mt < 4; ++mt) {
              Cvt av;
              av.u = *(const uint4*)&sm.At[buf][lane >> 4][(mt + ti) * 17 + (lane & 15) + tj][0];
              acc[mt] = __builtin_amdgcn_mfma_f32_16x16x32_f16(av.h, bw.h, acc[mt], 0, 0, 0);
            }
          }
        }
      }
    }
    if (ch < 3) write_chunk(buf ^ 1);
    __syncthreads();
    buf ^= 1;
  }

  // epilogue: transpose via padded LDS, f16 NHWC stores + bias
#pragma unroll
  for (int mt = 0; mt < 4; ++mt)
#pragma unroll
    for (int r = 0; r < 4; ++r)
      sm.accs[oq][lane & 15][mt * 16 + (lane >> 4) * 4 + r] = acc[mt][r];
  __syncthreads();

  const int yo = 2 * (ty + (lane >> 4)) + pyv;
  const int xo = 2 * (tx + (lane & 15)) + pxv;
  unsigned short* dst = upb + (((size_t)b * HO + yo) * HO + xo) * CO + oq * 16;
  unsigned rw[8];
#pragma unroll
  for (int p = 0; p < 8; ++p) {
    float v0 = sm.accs[oq][2 * p][lane] + bup[oq * 16 + 2 * p];
    float v1 = sm.accs[oq][2 * p + 1][lane] + bup[oq * 16 + 2 * p + 1];
    rw[p] = pkh(v0, v1);
  }
  *(uint4*)dst = make_uint4(rw[0], rw[1], rw[2], rw[3]);
  *(uint4*)(dst + 8) = make_uint4(rw[4], rw[5], rw[6], rw[7]);
}

// ---------------- K2: FUSED offset-conv (MFMA) + modulated deformable conv --------
// Tile 64 px (16x4), 1D grid 1024 XCD-swizzled. fo never leaves LDS.
// Best-known (r17): single-tap Vt dbuf, issue(k+2) deep pipeline, s_setprio(1)
// around phase-3 MFMA clusters, LDS 31744 B -> 5 blocks/CU.
__global__ __launch_bounds__(256) void k_offdcn(const float* __restrict__ boff,
                                                const float* __restrict__ bal,
                                                float* __restrict__ out,
                                                const float* __restrict__ ws) {
  __shared__ float smem[7936];          // 31744 B
  unsigned short* us_in = (unsigned short*)smem;
  float* fo_raw = smem;                                    // [32][66]
  unsigned* prm = (unsigned*)(smem + 2112);                // [9][64][3]
  unsigned short* us_vt = (unsigned short*)(smem + 3840);  // [2][8][64][8]

  const unsigned short* upb = (const unsigned short*)(ws + UPB);
  const unsigned short* lob = (const unsigned short*)(ws + LOB);
  const uint4* wfo = (const uint4*)(ws + WFOF);
  const uint4* wf  = (const uint4*)(ws + WFRG);

  const int t = threadIdx.x;
  const int lane = t & 63;
  const int w = __builtin_amdgcn_readfirstlane(t >> 6);
  const int mh = w >> 1, nt = w & 1;    // phase-1 roles
  const int oq = w;                     // phase-3 role
  const int orig = blockIdx.x;
  const int tile = ((orig & 7) << 7) + (orig >> 3);   // XCD swizzle (1024 = 8*128)
  const int tX = (tile & 7) * 16;
  const int tY = ((tile >> 3) & 31) * 4;
  const int b  = tile >> 8;
  const unsigned short* upB = upb + (size_t)b * HW * CO;

  union Cvt { uint4 u; half8 h; };

  // ================= phase 1: 3x3 conv over concat(up,low) -> fo_raw ==============
  for (int i = t; i < 16 * 108; i += 256) {
    int px = i >> 4, cg = i & 15;
    int gy = tY - 1 + px / 18, gx = tX - 1 + px % 18;
    uint4 v = make_uint4(0, 0, 0, 0);
    if (gy >= 0 && gy < HO && gx >= 0 && gx < HO) {
      const unsigned short* src =
          (cg < 8 ? upb : lob) + (((size_t)b * HO + gy) * HO + gx) * CO + (cg & 7) * 8;
      v = *(const uint4*)src;
    }
    *(uint4*)&us_in[((size_t)cg * 108 + px) * 8] = v;
  }
  __syncthreads();

  f32x4 acc2[2];
  acc2[0] = {0.f, 0.f, 0.f, 0.f}; acc2[1] = {0.f, 0.f, 0.f, 0.f};
#pragma unroll 1
  for (int tap = 0; tap < 9; ++tap) {
    int ky = tap / 3, kx = tap % 3;
#pragma unroll
    for (int kc = 0; kc < 4; ++kc) {
      Cvt bw; bw.u = wfo[(((size_t)tap * 4 + kc) * 2 + nt) * 64 + lane];
#pragma unroll
      for (int mt = 0; mt < 2; ++mt) {
        int sy = mh * 2 + mt;
        Cvt av;
        av.u = *(const uint4*)&us_in[(((size_t)(kc * 4 + (lane >> 4))) * 108 +
                                      (sy + ky) * 18 + (lane & 15) + kx) * 8];
        acc2[mt] = __builtin_amdgcn_mfma_f32_16x16x32_f16(av.h, bw.h, acc2[mt], 0, 0, 0);
      }
    }
  }
  __syncthreads();

#pragma unroll
  for (int mt = 0; mt < 2; ++mt)
#pragma unroll
    for (int r = 0; r < 4; ++r)
      fo_raw[(nt * 16 + (lane & 15)) * 66 + mh * 32 + mt * 16 + (lane >> 4) * 4 + r] =
          acc2[mt][r];
  __syncthreads();

  // ================= phase 2: bilinear params from LDS fo ==========================
  for (int i = t; i < 9 * 64; i += 256) {
    int k = i >> 6, px = i & 63;
    int y = tY + (px >> 4), x = tX + (px & 15);
    float offy = fo_raw[(2 * k) * 66 + px] + boff[2 * k];
    float offx = fo_raw[(2 * k + 1) * 66 + px] + boff[2 * k + 1];
    float m = 2.f / (1.f + expf(-(fo_raw[(18 + k) * 66 + px] + boff[18 + k])));
    float pyf = offy + (float)(y - 1 + k / 3);
    float pxf = offx + (float)(x - 1 + k % 3);
    float y0f = floorf(pyf), x0f = floorf(pxf);
    float wy = pyf - y0f, wx = pxf - x0f;
    int y0 = (int)y0f, x0 = (int)x0f;
    int y1 = y0 + 1, x1 = x0 + 1;
    float vy0 = (y0 >= 0 && y0 < HO) ? m : 0.f;
    float vy1 = (y1 >= 0 && y1 < HO) ? m : 0.f;
    float vx0 = (x0 >= 0 && x0 < HO) ? 1.f : 0.f;
    float vx1 = (x1 >= 0 && x1 < HO) ? 1.f : 0.f;
    float w0 = (1.f - wy) * (1.f - wx) * vy0 * vx0;
    float w1 = (1.f - wy) * wx * vy0 * vx1;
    float w2 = wy * (1.f - wx) * vy1 * vx0;
    float w3 = wy * wx * vy1 * vx1;
    int cy0 = min(max(y0, 0), HO - 1), cy1 = min(max(y1, 0), HO - 1);
    int cx0 = min(max(x0, 0), HO - 1), cx1 = min(max(x1, 0), HO - 1);
    unsigned pc = (unsigned)cy0 | ((unsigned)cy1 << 8) |
                  ((unsigned)cx0 << 16) | ((unsigned)cx1 << 24);
    unsigned* pr = prm + ((size_t)k * 64 + px) * 3;
    pr[0] = pkh(w0, w1);
    pr[1] = pkh(w2, w3);
    pr[2] = pc;
  }
  __syncthreads();

  // ================= phase 3: deformable gathers + packed-f16 bilinear + MFMA =====
  uint4 u00[2], u01[2], u10[2], u11[2];

  auto issue = [&](int k) {        // f16 gathers: 8 lanes x 16B = 128B runs per corner
#pragma unroll
    for (int it = 0; it < 2; ++it) {
      int j = it * 256 + t;
      int q = j & 7, px = j >> 3;
      unsigned pc = prm[((size_t)k * 64 + px) * 3 + 2];
      int cy0 = pc & 255, cy1 = (pc >> 8) & 255, cx0 = (pc >> 16) & 255, cx1 = pc >> 24;
      const unsigned short* base = upB + q * 8;
      u00[it] = *(const uint4*)(base + (size_t)(cy0 * HO + cx0) * CO);
      u01[it] = *(const uint4*)(base + (size_t)(cy0 * HO + cx1) * CO);
      u10[it] = *(const uint4*)(base + (size_t)(cy1 * HO + cx0) * CO);
      u11[it] = *(const uint4*)(base + (size_t)(cy1 * HO + cx1) * CO);
    }
  };

  auto combine = [&](int k, int buf) {
#pragma unroll
    for (int it = 0; it < 2; ++it) {
      int j = it * 256 + t;
      int q = j & 7, px = j >> 3;
      const unsigned* pr = prm + ((size_t)k * 64 + px) * 3;
      unsigned pw01 = pr[0], pw23 = pr[1];
      h2 w0 = dup_lo(pw01), w1 = dup_hi(pw01);
      h2 w2 = dup_lo(pw23), w3 = dup_hi(pw23);
      unsigned a0[4] = {u00[it].x, u00[it].y, u00[it].z, u00[it].w};
      unsigned a1[4] = {u01[it].x, u01[it].y, u01[it].z, u01[it].w};
      unsigned a2[4] = {u10[it].x, u10[it].y, u10[it].z, u10[it].w};
      unsigned a3[4] = {u11[it].x, u11[it].y, u11[it].z, u11[it].w};
      unsigned rw[4];
#pragma unroll
      for (int p = 0; p < 4; ++p) {       // 4x v_pk_fma_f16 per pair of channels
        h2 r = w3 * u2h(a3[p]);
        r = __builtin_elementwise_fma(w2, u2h(a2[p]), r);
        r = __builtin_elementwise_fma(w1, u2h(a1[p]), r);
        r = __builtin_elementwise_fma(w0, u2h(a0[p]), r);
        rw[p] = h2u(r);
      }
      *(uint4*)&us_vt[(((size_t)buf * 8 + q) * 64 + px) * 8] = make_uint4(rw[0], rw[1], rw[2], rw[3]);
    }
  };

  f32x4 acc[4];
#pragma unroll
  for (int mt = 0; mt < 4; ++mt) acc[mt] = {0.f, 0.f, 0.f, 0.f};

  uint4 bw0 = wf[(oq * 18 + 0) * 64 + lane];
  uint4 bw1 = wf[(oq * 18 + 1) * 64 + lane];
  uint4 bn0, bn1;

  issue(0);
  combine(0, 0);
  issue(1);                       // tap-1 loads: in flight across barrier + MFMA(0)
  __syncthreads();

  int buf = 0;
#pragma unroll 1
  for (int k = 0; k < 9; ++k) {
    __builtin_amdgcn_s_setprio(1);        // T5: favor MFMA-entering wave
#pragma unroll
    for (int kb2 = 0; kb2 < 2; ++kb2) {
      Cvt bfr; bfr.u = kb2 ? bw1 : bw0;
#pragma unroll
      for (int mt = 0; mt < 4; ++mt) {
        Cvt av;
        av.u = *(const uint4*)&us_vt[(((size_t)buf * 8 + kb2 * 4 + (lane >> 4)) * 64 +
                                      mt * 16 + (lane & 15)) * 8];
        acc[mt] = __builtin_amdgcn_mfma_f32_16x16x32_f16(av.h, bfr.h, acc[mt], 0, 0, 0);
      }
    }
    __builtin_amdgcn_s_setprio(0);
    if (k < 8) {
      combine(k + 1, buf ^ 1);    // consume tap k+1 loads (issued last iteration)
      if (k < 7) issue(k + 2);    // refill: in flight across barrier + MFMA(k+1)
      bn0 = wf[(oq * 18 + 2 * k + 2) * 64 + lane];
      bn1 = wf[(oq * 18 + 2 * k + 3) * 64 + lane];
    }
    __syncthreads();
    bw0 = bn0; bw1 = bn1;
    buf ^= 1;
  }

  // ================= phase 4: epilogue =============================================
  float* accs = smem;                    // [4][16][65]
#pragma unroll
  for (int mt = 0; mt < 4; ++mt)
#pragma unroll
    for (int r = 0; r < 4; ++r)
      accs[((size_t)oq * 16 + (lane & 15)) * 65 + mt * 16 + (lane >> 4) * 4 + r] = acc[mt][r];
  __syncthreads();

  const int y = tY + (lane >> 4), x = tX + (lane & 15);
  float* ob = out + (size_t)b * 2 * CO * HW + (size_t)y * HO + x;
#pragma unroll
  for (int ol = 0; ol < 16; ++ol) {
    int o = oq * 16 + ol;
    float v = accs[((size_t)oq * 16 + ol) * 65 + lane] + bal[o];
    v = (v >= 0.f) ? v : 0.2f * v;                // leaky relu
    ob[(size_t)o * HW] = v;
  }
}

extern "C" void kernel_launch(void* const* d_in, const int* in_sizes, int n_in,
                              void* d_out, int out_size, void* d_ws, size_t ws_size,
                              hipStream_t stream) {
  const float* high = (const float*)d_in[0];
  const float* low  = (const float*)d_in[1];
  const float* wup  = (const float*)d_in[2];
  const float* bup  = (const float*)d_in[3];
  const float* woff = (const float*)d_in[4];
  const float* boff = (const float*)d_in[5];
  const float* wal  = (const float*)d_in[6];
  const float* bal  = (const float*)d_in[7];
  float* out = (float*)d_out;
  float* ws  = (float*)d_ws;

  k_prep<<<dim3(1312), dim3(256), 0, stream>>>(high, wup, woff, wal, ws);
  k_up<<<dim3(1536), dim3(256), 0, stream>>>(low, bup, out, ws);
  k_offdcn<<<dim3(1024), dim3(256), 0, stream>>>(boff, bal, out, ws);
}